// Round 4
// baseline (503.015 us; speedup 1.0000x reference)
//
#include <hip/hip_runtime.h>

#define NUM_BINS 256
#define NPI (3*512*512)   // 786432 elements per image
#define TPB 256
#define NIMG 64
#define MMB 32            // minmax blocks per image
#define HB 16             // hist blocks per image
#define GVEC 4            // float4 per thread in gather

// Must bit-match the f32 reference: (v-mn)*255 / (mx-mn+1e-8), clip, trunc.
// Keep the real division — reciprocal precompute shifts boundary bins and we
// only have 0.0024 of absmax headroom (absmax 0.0176 vs threshold 0.02).
__device__ __forceinline__ int bin_of(float v, float mn, float denom) {
  float norm = (v - mn) * 255.0f / denom;
  norm = fminf(fmaxf(norm, 0.0f), 255.0f);
  return (int)norm;
}

// Pass 1: per-block min/max partials (no atomics). Also zero hist/done for pass 2.
__global__ void minmax_k(const float4* __restrict__ x, float2* __restrict__ partials,
                         int* __restrict__ hist, int* __restrict__ done) {
  const int chunk4 = NPI / 4 / MMB;  // 6144 float4 per block
  int img = blockIdx.x / MMB;
  int blk = blockIdx.x % MMB;
  const float4* p = x + (size_t)img * (NPI/4) + (size_t)blk * chunk4;

  float mn0 = 3.4e38f, mx0 = -3.4e38f, mn1 = 3.4e38f, mx1 = -3.4e38f;
  for (int i = threadIdx.x; i < chunk4; i += TPB * 2) {  // 12 iters, 2 indep loads
    float4 a = p[i];
    float4 b = p[i + TPB];
    mn0 = fminf(mn0, fminf(fminf(a.x, a.y), fminf(a.z, a.w)));
    mx0 = fmaxf(mx0, fmaxf(fmaxf(a.x, a.y), fmaxf(a.z, a.w)));
    mn1 = fminf(mn1, fminf(fminf(b.x, b.y), fminf(b.z, b.w)));
    mx1 = fmaxf(mx1, fmaxf(fmaxf(b.x, b.y), fmaxf(b.z, b.w)));
  }
  float mn = fminf(mn0, mn1), mx = fmaxf(mx0, mx1);
  for (int off = 32; off > 0; off >>= 1) {
    mn = fminf(mn, __shfl_down(mn, off));
    mx = fmaxf(mx, __shfl_down(mx, off));
  }
  __shared__ float smn[4], smx[4];
  int wave = threadIdx.x >> 6, lane = threadIdx.x & 63;
  if (lane == 0) { smn[wave] = mn; smx[wave] = mx; }
  __syncthreads();
  if (threadIdx.x == 0) {
    mn = fminf(fminf(smn[0], smn[1]), fminf(smn[2], smn[3]));
    mx = fmaxf(fmaxf(smx[0], smx[1]), fmaxf(smx[2], smx[3]));
    partials[blockIdx.x] = make_float2(mn, mx);
  }
  // zero global hist + done counters (visible to next dispatch via stream order)
  if (blockIdx.x < NIMG) {
    hist[blockIdx.x * NUM_BINS + threadIdx.x] = 0;
    if (threadIdx.x == 0) done[blockIdx.x] = 0;
  }
}

// Pass 2: histogram with wave-private LDS hists; last block per image does the scan.
__global__ void hist_k(const float4* __restrict__ x, const float2* __restrict__ partials,
                       int* __restrict__ hist, int* __restrict__ done,
                       float* __restrict__ cdfn) {
  __shared__ int wh[4 * NUM_BINS];   // one 256-bin hist per wave
  __shared__ int sdone;
  const int chunk4 = NPI / 4 / HB;   // 12288 float4 per block
  int img = blockIdx.x / HB;
  int blk = blockIdx.x % HB;

  // redundant per-block reduce of this image's partials (broadcast loads, L2-hot)
  float mn = 3.4e38f, mx = -3.4e38f;
  for (int j = 0; j < MMB; ++j) {
    float2 pm = partials[img * MMB + j];
    mn = fminf(mn, pm.x);
    mx = fmaxf(mx, pm.y);
  }
  float denom = mx - mn + 1e-8f;

  for (int i = threadIdx.x; i < 4 * NUM_BINS; i += TPB) wh[i] = 0;
  __syncthreads();

  int* myh = wh + (threadIdx.x >> 6) * NUM_BINS;  // wave-private
  const float4* p = x + (size_t)img * (NPI/4) + (size_t)blk * chunk4;
  for (int i = threadIdx.x; i < chunk4; i += TPB * 4) {
    float4 v0 = p[i];
    float4 v1 = p[i + TPB];
    float4 v2 = p[i + 2*TPB];
    float4 v3 = p[i + 3*TPB];
    atomicAdd(&myh[bin_of(v0.x, mn, denom)], 1);
    atomicAdd(&myh[bin_of(v0.y, mn, denom)], 1);
    atomicAdd(&myh[bin_of(v0.z, mn, denom)], 1);
    atomicAdd(&myh[bin_of(v0.w, mn, denom)], 1);
    atomicAdd(&myh[bin_of(v1.x, mn, denom)], 1);
    atomicAdd(&myh[bin_of(v1.y, mn, denom)], 1);
    atomicAdd(&myh[bin_of(v1.z, mn, denom)], 1);
    atomicAdd(&myh[bin_of(v1.w, mn, denom)], 1);
    atomicAdd(&myh[bin_of(v2.x, mn, denom)], 1);
    atomicAdd(&myh[bin_of(v2.y, mn, denom)], 1);
    atomicAdd(&myh[bin_of(v2.z, mn, denom)], 1);
    atomicAdd(&myh[bin_of(v2.w, mn, denom)], 1);
    atomicAdd(&myh[bin_of(v3.x, mn, denom)], 1);
    atomicAdd(&myh[bin_of(v3.y, mn, denom)], 1);
    atomicAdd(&myh[bin_of(v3.z, mn, denom)], 1);
    atomicAdd(&myh[bin_of(v3.w, mn, denom)], 1);
  }
  __syncthreads();

  int t = threadIdx.x;
  int s = wh[t] + wh[NUM_BINS + t] + wh[2*NUM_BINS + t] + wh[3*NUM_BINS + t];
  atomicAdd(&hist[img * NUM_BINS + t], s);  // device-scope
  __syncthreads();
  __threadfence();
  if (t == 0) sdone = atomicAdd(&done[img], 1);
  __syncthreads();

  if (sdone == HB - 1) {
    // last-arriving block for this image: all hist atomics complete. Scan.
    int* sh = wh;  // reuse LDS
    sh[t] = atomicAdd(&hist[img * NUM_BINS + t], 0);  // coherent read-back
    __syncthreads();
    for (int off = 1; off < NUM_BINS; off <<= 1) {
      int add = (t >= off) ? sh[t - off] : 0;
      __syncthreads();
      sh[t] += add;
      __syncthreads();
    }
    int cdf = sh[t], c0 = sh[0], cN = sh[NUM_BINS - 1];
    // counts are exact ints < 2^24: int math == the reference's f32 cumsum
    cdfn[img * NUM_BINS + t] = (float)(cdf - c0) / ((float)(cN - c0) + 1e-8f);
  }
}

// Pass 3: gather via LDS cdf table.
__global__ void gather_k(const float4* __restrict__ x, const float2* __restrict__ partials,
                         const float* __restrict__ cdfn, float4* __restrict__ out) {
  __shared__ float c[NUM_BINS];
  const int f4pi = NPI / 4;              // 196608
  const int CHUNK = TPB * GVEC;          // 1024 float4 per block
  const int bpi = f4pi / CHUNK;          // 192 blocks per image
  int img = blockIdx.x / bpi;
  int blk = blockIdx.x % bpi;
  c[threadIdx.x] = cdfn[img * NUM_BINS + threadIdx.x];  // TPB == NUM_BINS

  float mn = 3.4e38f, mx = -3.4e38f;
  for (int j = 0; j < MMB; ++j) {
    float2 pm = partials[img * MMB + j];
    mn = fminf(mn, pm.x);
    mx = fmaxf(mx, pm.y);
  }
  float denom = mx - mn + 1e-8f;
  __syncthreads();

  size_t base = (size_t)img * f4pi + (size_t)blk * CHUNK + threadIdx.x;
  #pragma unroll
  for (int j = 0; j < GVEC; ++j) {
    float4 v = x[base + (size_t)j * TPB];
    float4 o;
    o.x = c[bin_of(v.x, mn, denom)];
    o.y = c[bin_of(v.y, mn, denom)];
    o.z = c[bin_of(v.z, mn, denom)];
    o.w = c[bin_of(v.w, mn, denom)];
    out[base + (size_t)j * TPB] = o;
  }
}

extern "C" void kernel_launch(void* const* d_in, const int* in_sizes, int n_in,
                              void* d_out, int out_size, void* d_ws, size_t ws_size,
                              hipStream_t stream) {
  const float4* x = (const float4*)d_in[0];
  float4* out = (float4*)d_out;

  // ws: [partials: NIMG*MMB float2][hist: NIMG*256 int][done: NIMG int][cdfn: NIMG*256 f32]
  char* w = (char*)d_ws;
  float2* partials = (float2*)w;                    w += (size_t)NIMG * MMB * sizeof(float2);
  int*    hist     = (int*)w;                       w += (size_t)NIMG * NUM_BINS * sizeof(int);
  int*    done     = (int*)w;                       w += (size_t)NIMG * sizeof(int);
  float*  cdfn     = (float*)w;

  minmax_k<<<NIMG * MMB, TPB, 0, stream>>>(x, partials, hist, done);
  hist_k  <<<NIMG * HB,  TPB, 0, stream>>>(x, partials, hist, done, cdfn);
  gather_k<<<NIMG * (NPI/4/(TPB*GVEC)), TPB, 0, stream>>>(x, partials, cdfn, out);
}